// Round 1
// baseline (2527.541 us; speedup 1.0000x reference)
//
#include <hip/hip_runtime.h>
#include <hip/hip_bf16.h>

typedef __attribute__((ext_vector_type(8))) short short8;   // 8 x bf16 (4 VGPRs)
typedef __attribute__((ext_vector_type(4))) float float4v;  // 4 x f32 acc

// float -> bf16, round-to-nearest-even (inputs are finite; no NaN path needed)
__device__ __forceinline__ ushort f2b(float f) {
    union { float f; unsigned u; } v; v.f = f;
    return (ushort)((v.u + 0x7FFFu + ((v.u >> 16) & 1u)) >> 16);
}

// ---------------------------------------------------------------------------
// Stage a 128x32 bf16 tile (row-major, row stride ldk elements) into LDS via
// global_load_lds width=16. LDS layout: [128][32] contiguous (64 B/row).
// Lane l of wave w writes LDS bytes (w*64 + r*256 + l)*16 -> wave-uniform
// base + lane*16, satisfying the global_load_lds constraint.
// ---------------------------------------------------------------------------
__device__ __forceinline__ void stage128x32(const ushort* __restrict__ g, int ldk,
                                            ushort* lds, int tid) {
#pragma unroll
    for (int r = 0; r < 2; ++r) {
        int s   = tid + r * 256;     // 0..511 : 16-byte segment index
        int row = s >> 2;            // 0..127
        int ks  = s & 3;             // which 16B of the 64B row
        const char* gp = (const char*)(g + (size_t)row * ldk) + ks * 16;
        __builtin_amdgcn_global_load_lds(
            (__attribute__((address_space(1))) void*)gp,
            (__attribute__((address_space(3))) void*)(lds + (size_t)s * 8),
            16, 0, 0);
    }
}

// ---------------------------------------------------------------------------
// C = A * B^T with A:[M,K] bf16 row-major, Bm:[N,K] bf16 row-major.
// 128x128 tile, BK=32, 4 waves in 2x2, each wave 4x4 of 16x16x32 MFMA.
// EPI=0: H[m,n] = bf16(gelu(C + bias[n]))
// EPI=1: atomicAdd(lossp, sum over block of |C + bias[n] - teacher| * maskbit)
// ---------------------------------------------------------------------------
template <int EPI>
__global__ __launch_bounds__(256) void gemm_bt(
    const ushort* __restrict__ A, const ushort* __restrict__ Bm,
    int N, int K, const float* __restrict__ bias,
    ushort* __restrict__ H,
    const float* __restrict__ teacher, const unsigned* __restrict__ Mw,
    float* __restrict__ lossp)
{
    __shared__ alignas(16) ushort As[128 * 32];
    __shared__ alignas(16) ushort Bs[128 * 32];

    const int tid  = threadIdx.x;
    const int lane = tid & 63, wave = tid >> 6;
    const int qd   = lane >> 4, r16 = lane & 15;
    const int wm   = (wave >> 1) * 64;   // wave m-offset in tile
    const int wn   = (wave & 1) * 64;    // wave n-offset in tile
    const size_t tile_m = (size_t)blockIdx.y * 128;
    const size_t tile_n = (size_t)blockIdx.x * 128;

    const ushort* Ag = A  + tile_m * K;
    const ushort* Bg = Bm + tile_n * K;

    float4v acc[4][4];
#pragma unroll
    for (int i = 0; i < 4; ++i)
#pragma unroll
        for (int j = 0; j < 4; ++j) acc[i][j] = 0;

    for (int k0 = 0; k0 < K; k0 += 32) {
        stage128x32(Ag + k0, K, As, tid);
        stage128x32(Bg + k0, K, Bs, tid);
        __syncthreads();   // compiler drains vmcnt(0) before s_barrier

        short8 af[4], bf[4];
#pragma unroll
        for (int i = 0; i < 4; ++i)
            af[i] = *(const short8*)&As[(wm + i * 16 + r16) * 32 + qd * 8];
#pragma unroll
        for (int j = 0; j < 4; ++j)
            bf[j] = *(const short8*)&Bs[(wn + j * 16 + r16) * 32 + qd * 8];

#pragma unroll
        for (int i = 0; i < 4; ++i)
#pragma unroll
            for (int j = 0; j < 4; ++j)
                acc[i][j] = __builtin_amdgcn_mfma_f32_16x16x32_bf16(
                    af[i], bf[j], acc[i][j], 0, 0, 0);
        __syncthreads();
    }

    // C/D layout (verified m89/m91): col = lane&15, row = (lane>>4)*4 + reg
    if constexpr (EPI == 0) {
#pragma unroll
        for (int j = 0; j < 4; ++j) {
            const int n = (int)tile_n + wn + j * 16 + r16;
            const float bv = bias[n];
#pragma unroll
            for (int i = 0; i < 4; ++i) {
                const size_t mb = tile_m + wm + i * 16 + qd * 4;
#pragma unroll
                for (int r = 0; r < 4; ++r) {
                    float x = acc[i][j][r] + bv;
                    float g = 0.5f * x * (1.0f + erff(x * 0.7071067811865475f));
                    H[(mb + r) * (size_t)N + n] = f2b(g);
                }
            }
        }
    } else {
        float lsum = 0.0f;
        const int nw = N >> 5;
#pragma unroll
        for (int j = 0; j < 4; ++j) {
            const int n = (int)tile_n + wn + j * 16 + r16;
            const float bv = bias[n];
#pragma unroll
            for (int i = 0; i < 4; ++i) {
                const size_t mb = tile_m + wm + i * 16 + qd * 4;
#pragma unroll
                for (int r = 0; r < 4; ++r) {
                    const size_t m = mb + r;
                    const unsigned w = Mw[m * nw + (n >> 5)];
                    if ((w >> (n & 31)) & 1u) {
                        float p = acc[i][j][r] + bv;
                        lsum += fabsf(p - teacher[m * (size_t)N + n]);
                    }
                }
            }
        }
#pragma unroll
        for (int off = 32; off >= 1; off >>= 1) lsum += __shfl_down(lsum, off, 64);
        __shared__ float red[4];
        if (lane == 0) red[wave] = lsum;
        __syncthreads();
        if (tid == 0) atomicAdd(lossp, red[0] + red[1] + red[2] + red[3]);
    }
}

// ---------------------------------------------------------------------------
// Per-row (D=4096) top-1024-smallest mask + masked bf16 cast of student.
// rank<1024 under stable argsort == 1024 smallest values, ties -> lower index.
// Binary search over uint-ordered float bits for the 1024th order statistic.
// ---------------------------------------------------------------------------
__global__ __launch_bounds__(256) void mask_cast_kernel(
    const float* __restrict__ noise, const float* __restrict__ student,
    ushort* __restrict__ Xb, unsigned* __restrict__ Mw)
{
    const int row = blockIdx.x;
    const unsigned* nb = (const unsigned*)noise + (size_t)row * 4096;
    const float* srow  = student + (size_t)row * 4096;

    __shared__ unsigned u[4096];
    __shared__ unsigned char flag[4096];
    __shared__ int red[2][4];

    const int tid = threadIdx.x, lane = tid & 63, wave = tid >> 6;
    unsigned v[16];
#pragma unroll
    for (int i = 0; i < 16; ++i) { v[i] = nb[tid + 256 * i]; u[tid + 256 * i] = v[i]; }
    __syncthreads();

    // smallest V with count(u <= V) >= 1024; noise in [0,1) so hi=bits(1.0f)
    unsigned lo = 0, hi = 0x3F800000u;
    for (int it = 0; it < 32 && lo < hi; ++it) {
        const unsigned mid = lo + ((hi - lo) >> 1);
        int c = 0;
#pragma unroll
        for (int i = 0; i < 16; ++i) c += (v[i] <= mid);
#pragma unroll
        for (int off = 32; off >= 1; off >>= 1) c += __shfl_down(c, off, 64);
        if (lane == 0) red[it & 1][wave] = c;
        __syncthreads();
        const int total = red[it & 1][0] + red[it & 1][1] + red[it & 1][2] + red[it & 1][3];
        if (total >= 1024) hi = mid; else lo = mid + 1;
    }
    const unsigned V = lo;

    int c2 = 0;
#pragma unroll
    for (int i = 0; i < 16; ++i) c2 += (v[i] < V);
#pragma unroll
    for (int off = 32; off >= 1; off >>= 1) c2 += __shfl_down(c2, off, 64);
    __syncthreads();
    if (lane == 0) red[0][wave] = c2;
    __syncthreads();
    const int need = 1024 - (red[0][0] + red[0][1] + red[0][2] + red[0][3]);

#pragma unroll
    for (int i = 0; i < 16; ++i) {
        const int j = tid + 256 * i;
        const unsigned x = v[i];
        int f;
        if (x < V) f = 1;
        else if (x == V) {      // stable tie-break: index order among equals
            int er = 0;
            for (int k = 0; k < j; ++k) er += (u[k] == V);
            f = (er < need) ? 1 : 0;
        } else f = 0;
        flag[j] = (unsigned char)f;
        Xb[(size_t)row * 4096 + j] = f ? (ushort)0 : f2b(srow[j]);
    }
    __syncthreads();
    if (tid < 128) {
        unsigned w = 0;
#pragma unroll
        for (int b = 0; b < 32; ++b) w |= ((unsigned)flag[tid * 32 + b]) << b;
        Mw[(size_t)row * 128 + tid] = w;
    }
}

__global__ __launch_bounds__(256) void cast_f32_bf16(
    const float* __restrict__ in, ushort* __restrict__ out, long n)
{
    long i = ((long)blockIdx.x * 256 + threadIdx.x) * 4;
    if (i >= n) return;
    float4 f = *(const float4*)(in + i);
    ushort4 o = make_ushort4(f2b(f.x), f2b(f.y), f2b(f.z), f2b(f.w));
    *(ushort4*)(out + i) = o;
}

__global__ void finalize_kernel(const float* __restrict__ lossp, float* __restrict__ out) {
    if (threadIdx.x == 0 && blockIdx.x == 0)
        out[0] = lossp[0] * (1.0f / 8388608.0f);   // B * 1024 masked entries
}

extern "C" void kernel_launch(void* const* d_in, const int* in_sizes, int n_in,
                              void* d_out, int out_size, void* d_ws, size_t ws_size,
                              hipStream_t stream) {
    (void)in_sizes; (void)n_in; (void)out_size; (void)ws_size;
    const float* student = (const float*)d_in[0];
    const float* teacher = (const float*)d_in[1];
    const float* noise   = (const float*)d_in[2];
    const float* W1      = (const float*)d_in[3];   // [8192,4096]
    const float* b1      = (const float*)d_in[4];
    const float* W2      = (const float*)d_in[5];   // [4096,8192]
    const float* b2      = (const float*)d_in[6];
    float* out = (float*)d_out;

    char* ws = (char*)d_ws;
    ushort*   Xb    = (ushort*)(ws);                    //  64 MB masked student bf16
    ushort*   Wb    = (ushort*)(ws + (64ull << 20));    //  64 MB W1b then W2b
    ushort*   Hb    = (ushort*)(ws + (128ull << 20));   // 128 MB gelu output bf16
    unsigned* Mw    = (unsigned*)(ws + (256ull << 20)); //   4 MB mask bits
    float*    lossp = (float*)(ws + (260ull << 20));

    hipMemsetAsync(lossp, 0, sizeof(float), stream);

    mask_cast_kernel<<<8192, 256, 0, stream>>>(noise, student, Xb, Mw);

    const long nW1 = 8192L * 4096L;
    cast_f32_bf16<<<(int)(nW1 / 1024), 256, 0, stream>>>(W1, Wb, nW1);

    // H = gelu(Xb @ W1^T + b1)  -> [8192, 8192] bf16
    gemm_bt<0><<<dim3(64, 64), 256, 0, stream>>>(Xb, Wb, 8192, 4096, b1,
                                                 Hb, nullptr, nullptr, nullptr);

    const long nW2 = 4096L * 8192L;
    cast_f32_bf16<<<(int)(nW2 / 1024), 256, 0, stream>>>(W2, Wb, nW2);

    // loss partials from pred = H @ W2^T + b2 vs teacher, masked L1
    gemm_bt<1><<<dim3(32, 64), 256, 0, stream>>>(Hb, Wb, 4096, 8192, b2,
                                                 nullptr, teacher, Mw, lossp);

    finalize_kernel<<<1, 64, 0, stream>>>(lossp, out);
}

// Round 2
// 2482.636 us; speedup vs baseline: 1.0181x; 1.0181x over previous
//
#include <hip/hip_runtime.h>
#include <hip/hip_bf16.h>

typedef __attribute__((ext_vector_type(8))) short short8;   // 8 x bf16 (4 VGPRs)
typedef __attribute__((ext_vector_type(4))) float float4v;  // 4 x f32 acc

// float -> bf16, round-to-nearest-even (inputs are finite; no NaN path needed)
__device__ __forceinline__ ushort f2b(float f) {
    union { float f; unsigned u; } v; v.f = f;
    return (ushort)((v.u + 0x7FFFu + ((v.u >> 16) & 1u)) >> 16);
}

// ---------------------------------------------------------------------------
// Stage a 128x32 bf16 tile (row-major, row stride ldk elements) into LDS via
// global_load_lds width=16, with an XOR bank swizzle.
// LDS layout: row r, 16B-segment slot ks holds global segment ks^((r>>1)&3).
// (global_load_lds requires lds = wave-uniform base + lane*16, so the
// permutation is applied to the *global* source address, not the LDS dest.)
// Read side: fragment for (row, qd) lives at row*64B + (qd^((row>>1)&3))*16B,
// which spreads 16 lanes over all 8 bank groups (2-way = conflict-free, m136).
// ---------------------------------------------------------------------------
__device__ __forceinline__ void stage128x32(const ushort* __restrict__ g, int ldk,
                                            ushort* lds, int tid) {
#pragma unroll
    for (int r = 0; r < 2; ++r) {
        int s     = tid + r * 256;   // 0..511 : LDS 16-byte slot index
        int row   = s >> 2;          // 0..127
        int kslot = s & 3;           // LDS slot within the 64B row
        int ks    = kslot ^ ((row >> 1) & 3);   // global segment fetched
        const char* gp = (const char*)(g + (size_t)row * ldk) + ks * 16;
        __builtin_amdgcn_global_load_lds(
            (__attribute__((address_space(1))) void*)gp,
            (__attribute__((address_space(3))) void*)(lds + (size_t)s * 8),
            16, 0, 0);
    }
}

// ---------------------------------------------------------------------------
// C = A * B^T with A:[M,K] bf16 row-major, Bm:[N,K] bf16 row-major.
// 128x128 tile, BK=32, 4 waves in 2x2, each wave 4x4 of 16x16x32 MFMA.
// EPI=0: H[m,n] = bf16(gelu(C + bias[n]))
// EPI=1: atomicAdd(lossp, sum over block of |C + bias[n] - teacher| * maskbit)
// ---------------------------------------------------------------------------
template <int EPI>
__global__ __launch_bounds__(256) void gemm_bt(
    const ushort* __restrict__ A, const ushort* __restrict__ Bm,
    int N, int K, const float* __restrict__ bias,
    ushort* __restrict__ H,
    const float* __restrict__ teacher, const unsigned* __restrict__ Mw,
    float* __restrict__ lossp)
{
    __shared__ alignas(16) ushort As[128 * 32];
    __shared__ alignas(16) ushort Bs[128 * 32];

    const int tid  = threadIdx.x;
    const int lane = tid & 63, wave = tid >> 6;
    const int qd   = lane >> 4, r16 = lane & 15;
    const int wm   = (wave >> 1) * 64;   // wave m-offset in tile
    const int wn   = (wave & 1) * 64;    // wave n-offset in tile
    const size_t tile_m = (size_t)blockIdx.y * 128;
    const size_t tile_n = (size_t)blockIdx.x * 128;

    const ushort* Ag = A  + tile_m * K;
    const ushort* Bg = Bm + tile_n * K;

    float4v acc[4][4];
#pragma unroll
    for (int i = 0; i < 4; ++i)
#pragma unroll
        for (int j = 0; j < 4; ++j) acc[i][j] = 0;

    for (int k0 = 0; k0 < K; k0 += 32) {
        stage128x32(Ag + k0, K, As, tid);
        stage128x32(Bg + k0, K, Bs, tid);
        __syncthreads();   // compiler drains vmcnt(0) before s_barrier

        short8 af[4], bf[4];
#pragma unroll
        for (int i = 0; i < 4; ++i) {
            const int row = wm + i * 16 + r16;
            af[i] = *(const short8*)&As[row * 32 + (qd ^ ((row >> 1) & 3)) * 8];
        }
#pragma unroll
        for (int j = 0; j < 4; ++j) {
            const int row = wn + j * 16 + r16;
            bf[j] = *(const short8*)&Bs[row * 32 + (qd ^ ((row >> 1) & 3)) * 8];
        }

#pragma unroll
        for (int i = 0; i < 4; ++i)
#pragma unroll
            for (int j = 0; j < 4; ++j)
                acc[i][j] = __builtin_amdgcn_mfma_f32_16x16x32_bf16(
                    af[i], bf[j], acc[i][j], 0, 0, 0);
        __syncthreads();
    }

    // C/D layout (verified m89/m91): col = lane&15, row = (lane>>4)*4 + reg
    if constexpr (EPI == 0) {
#pragma unroll
        for (int j = 0; j < 4; ++j) {
            const int n = (int)tile_n + wn + j * 16 + r16;
            const float bv = bias[n];
#pragma unroll
            for (int i = 0; i < 4; ++i) {
                const size_t mb = tile_m + wm + i * 16 + qd * 4;
#pragma unroll
                for (int r = 0; r < 4; ++r) {
                    float x = acc[i][j][r] + bv;
                    float g = 0.5f * x * (1.0f + erff(x * 0.7071067811865475f));
                    H[(mb + r) * (size_t)N + n] = f2b(g);
                }
            }
        }
    } else {
        float lsum = 0.0f;
        const int nw = N >> 5;
#pragma unroll
        for (int j = 0; j < 4; ++j) {
            const int n = (int)tile_n + wn + j * 16 + r16;
            const float bv = bias[n];
#pragma unroll
            for (int i = 0; i < 4; ++i) {
                const size_t mb = tile_m + wm + i * 16 + qd * 4;
#pragma unroll
                for (int r = 0; r < 4; ++r) {
                    const size_t m = mb + r;
                    const unsigned w = Mw[m * nw + (n >> 5)];
                    if ((w >> (n & 31)) & 1u) {
                        float p = acc[i][j][r] + bv;
                        lsum += fabsf(p - teacher[m * (size_t)N + n]);
                    }
                }
            }
        }
#pragma unroll
        for (int off = 32; off >= 1; off >>= 1) lsum += __shfl_down(lsum, off, 64);
        __shared__ float red[4];
        if (lane == 0) red[wave] = lsum;
        __syncthreads();
        if (tid == 0) atomicAdd(lossp, red[0] + red[1] + red[2] + red[3]);
    }
}

// ---------------------------------------------------------------------------
// Per-row (D=4096) top-1024-smallest mask + masked bf16 cast of student.
// rank<1024 under stable argsort == 1024 smallest values, ties -> lower index.
// Binary search over uint-ordered float bits for the 1024th order statistic.
// ---------------------------------------------------------------------------
__global__ __launch_bounds__(256) void mask_cast_kernel(
    const float* __restrict__ noise, const float* __restrict__ student,
    ushort* __restrict__ Xb, unsigned* __restrict__ Mw)
{
    const int row = blockIdx.x;
    const unsigned* nb = (const unsigned*)noise + (size_t)row * 4096;
    const float* srow  = student + (size_t)row * 4096;

    __shared__ unsigned u[4096];
    __shared__ unsigned char flag[4096];
    __shared__ int red[2][4];

    const int tid = threadIdx.x, lane = tid & 63, wave = tid >> 6;
    unsigned v[16];
#pragma unroll
    for (int i = 0; i < 16; ++i) { v[i] = nb[tid + 256 * i]; u[tid + 256 * i] = v[i]; }
    __syncthreads();

    // smallest V with count(u <= V) >= 1024; noise in [0,1) so hi=bits(1.0f)
    unsigned lo = 0, hi = 0x3F800000u;
    for (int it = 0; it < 32 && lo < hi; ++it) {
        const unsigned mid = lo + ((hi - lo) >> 1);
        int c = 0;
#pragma unroll
        for (int i = 0; i < 16; ++i) c += (v[i] <= mid);
#pragma unroll
        for (int off = 32; off >= 1; off >>= 1) c += __shfl_down(c, off, 64);
        if (lane == 0) red[it & 1][wave] = c;
        __syncthreads();
        const int total = red[it & 1][0] + red[it & 1][1] + red[it & 1][2] + red[it & 1][3];
        if (total >= 1024) hi = mid; else lo = mid + 1;
    }
    const unsigned V = lo;

    int c2 = 0;
#pragma unroll
    for (int i = 0; i < 16; ++i) c2 += (v[i] < V);
#pragma unroll
    for (int off = 32; off >= 1; off >>= 1) c2 += __shfl_down(c2, off, 64);
    __syncthreads();
    if (lane == 0) red[0][wave] = c2;
    __syncthreads();
    const int need = 1024 - (red[0][0] + red[0][1] + red[0][2] + red[0][3]);

#pragma unroll
    for (int i = 0; i < 16; ++i) {
        const int j = tid + 256 * i;
        const unsigned x = v[i];
        int f;
        if (x < V) f = 1;
        else if (x == V) {      // stable tie-break: index order among equals
            int er = 0;
            for (int k = 0; k < j; ++k) er += (u[k] == V);
            f = (er < need) ? 1 : 0;
        } else f = 0;
        flag[j] = (unsigned char)f;
        Xb[(size_t)row * 4096 + j] = f ? (ushort)0 : f2b(srow[j]);
    }
    __syncthreads();
    if (tid < 128) {
        unsigned w = 0;
#pragma unroll
        for (int b = 0; b < 32; ++b) w |= ((unsigned)flag[tid * 32 + b]) << b;
        Mw[(size_t)row * 128 + tid] = w;
    }
}

__global__ __launch_bounds__(256) void cast_f32_bf16(
    const float* __restrict__ in, ushort* __restrict__ out, long n)
{
    long i = ((long)blockIdx.x * 256 + threadIdx.x) * 4;
    if (i >= n) return;
    float4 f = *(const float4*)(in + i);
    ushort4 o = make_ushort4(f2b(f.x), f2b(f.y), f2b(f.z), f2b(f.w));
    *(ushort4*)(out + i) = o;
}

__global__ void finalize_kernel(const float* __restrict__ lossp, float* __restrict__ out) {
    if (threadIdx.x == 0 && blockIdx.x == 0)
        out[0] = lossp[0] * (1.0f / 8388608.0f);   // B * 1024 masked entries
}

extern "C" void kernel_launch(void* const* d_in, const int* in_sizes, int n_in,
                              void* d_out, int out_size, void* d_ws, size_t ws_size,
                              hipStream_t stream) {
    (void)in_sizes; (void)n_in; (void)out_size; (void)ws_size;
    const float* student = (const float*)d_in[0];
    const float* teacher = (const float*)d_in[1];
    const float* noise   = (const float*)d_in[2];
    const float* W1      = (const float*)d_in[3];   // [8192,4096]
    const float* b1      = (const float*)d_in[4];
    const float* W2      = (const float*)d_in[5];   // [4096,8192]
    const float* b2      = (const float*)d_in[6];
    float* out = (float*)d_out;

    char* ws = (char*)d_ws;
    ushort*   Xb    = (ushort*)(ws);                    //  64 MB masked student bf16
    ushort*   Wb    = (ushort*)(ws + (64ull << 20));    //  64 MB W1b then W2b
    ushort*   Hb    = (ushort*)(ws + (128ull << 20));   // 128 MB gelu output bf16
    unsigned* Mw    = (unsigned*)(ws + (256ull << 20)); //   4 MB mask bits
    float*    lossp = (float*)(ws + (260ull << 20));

    hipMemsetAsync(lossp, 0, sizeof(float), stream);

    mask_cast_kernel<<<8192, 256, 0, stream>>>(noise, student, Xb, Mw);

    const long nW1 = 8192L * 4096L;
    cast_f32_bf16<<<(int)(nW1 / 1024), 256, 0, stream>>>(W1, Wb, nW1);

    // H = gelu(Xb @ W1^T + b1)  -> [8192, 8192] bf16
    gemm_bt<0><<<dim3(64, 64), 256, 0, stream>>>(Xb, Wb, 8192, 4096, b1,
                                                 Hb, nullptr, nullptr, nullptr);

    const long nW2 = 4096L * 8192L;
    cast_f32_bf16<<<(int)(nW2 / 1024), 256, 0, stream>>>(W2, Wb, nW2);

    // loss partials from pred = H @ W2^T + b2 vs teacher, masked L1
    gemm_bt<1><<<dim3(32, 64), 256, 0, stream>>>(Hb, Wb, 4096, 8192, b2,
                                                 nullptr, teacher, Mw, lossp);

    finalize_kernel<<<1, 64, 0, stream>>>(lossp, out);
}